// Round 4
// baseline (568.353 us; speedup 1.0000x reference)
//
#include <hip/hip_runtime.h>
#include <hip/hip_bf16.h>

typedef __attribute__((ext_vector_type(8))) short short8;
typedef __attribute__((ext_vector_type(4))) float f32x4;

#define NN    2048
#define DDIM  512
#define HDIM  512
#define PP    51
#define NBASE 30
#define PD    26112   // PP*DDIM

static __device__ __forceinline__ short f2bf(float f) {
  __hip_bfloat16 h = __float2bfloat16(f);
  short s;
  __builtin_memcpy(&s, &h, 2);
  return s;
}

#define GLOAD16(gsrc, ldst)                                                              \
  __builtin_amdgcn_global_load_lds((const __attribute__((address_space(1))) void*)(gsrc),\
                                   (__attribute__((address_space(3))) void*)(ldst),      \
                                   16, 0, 0)

// ---------------------------------------------------------------------------
// K0: vertex [2048,512] f32 -> vT [512,2048] bf16
// ---------------------------------------------------------------------------
__global__ __launch_bounds__(256) void k_transpose(const float* __restrict__ vx,
                                                   short* __restrict__ vT) {
  __shared__ float tile[64][68];
  const int t  = threadIdx.x;
  const int mt = blockIdx.x & 31, dt = blockIdx.x >> 5;
  const int m0 = mt * 64, d0 = dt * 64;

  const int r  = t >> 2;
  const int c0 = (t & 3) * 16;
  const float* src = vx + (size_t)(m0 + r) * DDIM + d0 + c0;
#pragma unroll
  for (int j = 0; j < 4; ++j) {
    f32x4 v = *(const f32x4*)(src + j * 4);
    tile[r][c0 + j * 4 + 0] = v[0];
    tile[r][c0 + j * 4 + 1] = v[1];
    tile[r][c0 + j * 4 + 2] = v[2];
    tile[r][c0 + j * 4 + 3] = v[3];
  }
  __syncthreads();
  const int c  = t >> 2;
  const int r0 = (t & 3) * 16;
  short8 o0, o1;
#pragma unroll
  for (int j = 0; j < 8; ++j) {
    o0[j] = f2bf(tile[r0 + j][c]);
    o1[j] = f2bf(tile[r0 + 8 + j][c]);
  }
  short* dst = vT + (size_t)(d0 + c) * NN + m0 + r0;
  *(short8*)(dst)     = o0;
  *(short8*)(dst + 8) = o1;
}

// ---------------------------------------------------------------------------
// K1: BmT [512][26112] bf16 ; BmT[h][d'*51+p] = sum_b Wc[p,b]*W[(b*512+d')*512+h]
// ---------------------------------------------------------------------------
__global__ __launch_bounds__(512) void k_bmt(const float* __restrict__ W,
                                             const float* __restrict__ Wc,
                                             short* __restrict__ BmT) {
  __shared__ float wcs[PP * NBASE];
  __shared__ short Lt[HDIM * PP];
  const int t  = threadIdx.x;
  const int dp = blockIdx.x;

  for (int i = t; i < PP * NBASE; i += 512) wcs[i] = Wc[i];

  float wv[NBASE];
#pragma unroll
  for (int b = 0; b < NBASE; ++b)
    wv[b] = W[((size_t)(b * DDIM + dp)) * HDIM + t];
  __syncthreads();

#pragma unroll 1
  for (int p = 0; p < PP; ++p) {
    float acc = 0.f;
#pragma unroll
    for (int b = 0; b < NBASE; ++b) acc += wcs[p * NBASE + b] * wv[b];
    Lt[t * PP + p] = f2bf(acc);
  }
  __syncthreads();

  for (int idx = t; idx < HDIM * PP; idx += 512) {
    const int h = idx / PP;
    const int p = idx - h * PP;
    BmT[(size_t)h * PD + dp * PP + p] = Lt[idx];
  }
}

// ---------------------------------------------------------------------------
// K2: out[n,h] = B[h]
// ---------------------------------------------------------------------------
__global__ __launch_bounds__(512) void k_init(const float* __restrict__ B,
                                              float* __restrict__ out) {
  out[(size_t)blockIdx.x * HDIM + threadIdx.x] = B[threadIdx.x];
}

// ---------------------------------------------------------------------------
// G1: SF[n][p*512+d] = sum_m A[p,n,m]*vertex[m,d]
// grid 816 = 51p x 16n ; 1024 thr (16 waves 2x8) ; tile 128(n) x 512(d) x BK64
// NEVER-DRAIN schedule: per iter the VMEM queue holds 6..10 loads.
//   issue order per phase: A(kt+2) f32x4 x2 FIRST, then B(kt+2) gload_lds x4.
//   stage-A wait  = vmcnt(4)  (compiler-exact: A oldest, B(t+1) stays in flight)
//   pre-compute   = vmcnt(6)  (retires B(t); keeps A(t+2)+B(t+2))
// ---------------------------------------------------------------------------
__global__ __launch_bounds__(1024, 4) void g_supports(const float* __restrict__ A,
                                                      const short* __restrict__ vT,
                                                      short* __restrict__ SF) {
  __shared__ __align__(16) char Asb[128 * 64 * 2];        // 16 KB
  __shared__ __align__(16) char Bsb[2][512 * 64 * 2];     // 2 x 64 KB
  const int t    = threadIdx.x;
  const int p    = blockIdx.x >> 4;
  const int n0   = (blockIdx.x & 15) << 7;
  const int lane = t & 63, w = t >> 6;        // 16 waves
  const int wr = w >> 3, wc = w & 7;          // 2 x 8 wave grid
  const int l15 = lane & 15, q4 = lane >> 4;

  // A staging: thread t stages row t>>3 (128 rows, 8 thr/row), 8 f32 at col (t&7)*8
  const int arow = t >> 3;
  const int ac16 = (t & 7) << 4;
  char* aw = Asb + arow * 128 + (ac16 ^ ((arow & 7) << 4));
  const float* Arow = A + (size_t)p * NN * NN + (size_t)(n0 + arow) * NN + ((t & 7) << 3);

  f32x4 acc[4][4];
#pragma unroll
  for (int i = 0; i < 4; ++i)
#pragma unroll
    for (int j = 0; j < 4; ++j) acc[i][j] = (f32x4){0.f, 0.f, 0.f, 0.f};

  f32x4 ar0, ar1;

#define G1_ISSUE_A(kt)                                                             \
  {                                                                                \
    const f32x4* s = (const f32x4*)(Arow + (kt) * 64);                             \
    ar0 = s[0]; ar1 = s[1];                                                        \
  }

#define G1_ISSUE_B(buf, kt)                                                        \
  {                                                                                \
    _Pragma("unroll")                                                              \
    for (int i = 0; i < 4; ++i) {                                                  \
      const int L   = t * 16 + i * 16384;                                          \
      const int row = L >> 7;                                                      \
      const int cb  = L & 127;                                                     \
      const char* g = (const char*)vT + (size_t)row * (NN * 2) + (kt) * 128        \
                    + (cb ^ ((row & 7) << 4));                                     \
      GLOAD16(g, Bsb[buf] + L);                                                    \
    }                                                                              \
  }

#define G1_STAGE_A()                                                               \
  {                                                                                \
    short8 s0;                                                                     \
    _Pragma("unroll")                                                              \
    for (int j = 0; j < 4; ++j) {                                                  \
      s0[j]     = f2bf(ar0[j]);                                                    \
      s0[j + 4] = f2bf(ar1[j]);                                                    \
    }                                                                              \
    *(short8*)aw = s0;                                                             \
  }

#define G1_COMPUTE(buf)                                                            \
  {                                                                                \
    _Pragma("unroll")                                                              \
    for (int ks = 0; ks < 2; ++ks) {                                               \
      const int kb = ks * 64 + q4 * 16;                                            \
      short8 af[4], bfr[4];                                                        \
      _Pragma("unroll")                                                            \
      for (int mi = 0; mi < 4; ++mi) {                                             \
        const int row = wr * 64 + mi * 16 + l15;                                   \
        af[mi] = *(const short8*)(Asb + row * 128 + (kb ^ ((row & 7) << 4)));      \
      }                                                                            \
      _Pragma("unroll")                                                            \
      for (int ni = 0; ni < 4; ++ni) {                                             \
        const int row = wc * 64 + ni * 16 + l15;                                   \
        bfr[ni] = *(const short8*)(Bsb[buf] + row * 128 + (kb ^ ((row & 7) << 4)));\
      }                                                                            \
      _Pragma("unroll")                                                            \
      for (int mi = 0; mi < 4; ++mi)                                               \
        _Pragma("unroll")                                                          \
        for (int ni = 0; ni < 4; ++ni)                                             \
          acc[mi][ni] = __builtin_amdgcn_mfma_f32_16x16x32_bf16(af[mi], bfr[ni],   \
                                                                acc[mi][ni], 0, 0, 0);\
    }                                                                              \
  }

  // ---- prologue: establish steady-state queue [B(0)4, A(1)2, B(1)4] ----
  G1_ISSUE_A(0);                 // A(0) x2
  G1_ISSUE_B(0, 0);              // B(0) x4
  G1_STAGE_A();                  // waits A(0) only (vmcnt(4), compiler-exact)
  G1_ISSUE_A(1);                 // A(1) x2
  G1_ISSUE_B(1, 1);              // B(1) x4
  asm volatile("s_waitcnt lgkmcnt(0)" ::: "memory");
  __builtin_amdgcn_sched_barrier(0);

  for (int kt = 0; kt < 32; ++kt) {
    // B(kt) retired (own loads); keep newest 6 = A(kt+1 next)+B in flight
    asm volatile("s_waitcnt vmcnt(6)" ::: "memory");
    __builtin_amdgcn_sched_barrier(0);
    __builtin_amdgcn_s_barrier();          // Bsb[kt&1] + Asb(kt) visible to all
    __builtin_amdgcn_sched_barrier(0);

    __builtin_amdgcn_s_setprio(1);
    G1_COMPUTE(kt & 1);
    __builtin_amdgcn_s_setprio(0);

    __builtin_amdgcn_s_barrier();          // all waves done reading Asb/Bsb[kt&1]
    __builtin_amdgcn_sched_barrier(0);

    G1_STAGE_A();                          // stage A(kt+1); waits vmcnt(4) (B(kt+1) stays)
    const int nk = (kt + 2 < 32) ? (kt + 2) : 31;   // clamped: uniform counts
    G1_ISSUE_A(nk);                        // A first,
    G1_ISSUE_B(kt & 1, nk);                // then B into the buffer just freed
    asm volatile("s_waitcnt lgkmcnt(0)" ::: "memory");
    __builtin_amdgcn_sched_barrier(0);
  }

  // ---- epilogue: C row = 4*q4+qq, col = l15 ----
#pragma unroll
  for (int mi = 0; mi < 4; ++mi) {
    const int nr = n0 + wr * 64 + mi * 16 + q4 * 4;
#pragma unroll
    for (int ni = 0; ni < 4; ++ni) {
      const int dc = p * DDIM + wc * 64 + ni * 16 + l15;
#pragma unroll
      for (int qq = 0; qq < 4; ++qq)
        SF[(size_t)(nr + qq) * PD + dc] = f2bf(acc[mi][ni][qq]);
    }
  }
#undef G1_ISSUE_B
#undef G1_ISSUE_A
#undef G1_STAGE_A
#undef G1_COMPUTE
}

// ---------------------------------------------------------------------------
// G2: out[n,h] += sum_r SF[n,r]*BmT[h,r]   (round-1 proven version, unchanged)
// grid 544 = 17kc x 16n x 2h ; tile 128 x 256 x BK64 ; 48 KB LDS, 3 blk/CU
// ---------------------------------------------------------------------------
__global__ __launch_bounds__(512) void g_out(const short* __restrict__ SF,
                                             const short* __restrict__ BmT,
                                             float* __restrict__ out) {
  __shared__ __align__(16) char Asb[128 * 64 * 2];
  __shared__ __align__(16) char Bsb[256 * 64 * 2];
  const int t   = threadIdx.x;
  const int bid = blockIdx.x;
  const int kc  = bid >> 5;
  const int rem = bid & 31;
  const int n0  = (rem >> 1) * 128;
  const int h0  = (rem & 1) * 256;
  const int rbase = kc * 1536;
  const int lane = t & 63, w = t >> 6;
  const int wr = w >> 2, wc = w & 3;
  const int l15 = lane & 15, q4 = lane >> 4;

  f32x4 acc[4][4];
#pragma unroll
  for (int i = 0; i < 4; ++i)
#pragma unroll
    for (int j = 0; j < 4; ++j) acc[i][j] = (f32x4){0.f, 0.f, 0.f, 0.f};

  for (int kt = 0; kt < 24; ++kt) {
    const int rk = rbase + (kt << 6);
    __syncthreads();
#pragma unroll
    for (int i = 0; i < 2; ++i) {
      const int L   = t * 16 + i * 8192;
      const int row = L >> 7, cb = L & 127;
      const char* g = (const char*)SF + ((size_t)(n0 + row) * PD + rk) * 2
                    + (cb ^ ((row & 7) << 4));
      GLOAD16(g, Asb + L);
    }
#pragma unroll
    for (int i = 0; i < 4; ++i) {
      const int L   = t * 16 + i * 8192;
      const int row = L >> 7, cb = L & 127;
      const char* g = (const char*)BmT + ((size_t)(h0 + row) * PD + rk) * 2
                    + (cb ^ ((row & 7) << 4));
      GLOAD16(g, Bsb + L);
    }
    __syncthreads();
#pragma unroll
    for (int ks = 0; ks < 2; ++ks) {
      const int kb = ks * 64 + q4 * 16;
      short8 af[4], bfr[4];
#pragma unroll
      for (int mi = 0; mi < 4; ++mi) {
        const int row = wr * 64 + mi * 16 + l15;
        af[mi] = *(const short8*)(Asb + row * 128 + (kb ^ ((row & 7) << 4)));
      }
#pragma unroll
      for (int ni = 0; ni < 4; ++ni) {
        const int row = wc * 64 + ni * 16 + l15;
        bfr[ni] = *(const short8*)(Bsb + row * 128 + (kb ^ ((row & 7) << 4)));
      }
#pragma unroll
      for (int mi = 0; mi < 4; ++mi)
#pragma unroll
        for (int ni = 0; ni < 4; ++ni)
          acc[mi][ni] = __builtin_amdgcn_mfma_f32_16x16x32_bf16(af[mi], bfr[ni],
                                                                acc[mi][ni], 0, 0, 0);
    }
  }

#pragma unroll
  for (int mi = 0; mi < 4; ++mi) {
    const int nr = n0 + wr * 64 + mi * 16 + q4 * 4;
#pragma unroll
    for (int ni = 0; ni < 4; ++ni) {
      const int hc = h0 + wc * 64 + ni * 16 + l15;
#pragma unroll
      for (int qq = 0; qq < 4; ++qq)
        atomicAdd(&out[(size_t)(nr + qq) * HDIM + hc], acc[mi][ni][qq]);
    }
  }
}

// ---------------------------------------------------------------------------
extern "C" void kernel_launch(void* const* d_in, const int* in_sizes, int n_in,
                              void* d_out, int out_size, void* d_ws, size_t ws_size,
                              hipStream_t stream) {
  const float* vertex = (const float*)d_in[0];
  const float* A      = (const float*)d_in[1];
  const float* W      = (const float*)d_in[2];
  const float* Wc     = (const float*)d_in[3];
  const float* B      = (const float*)d_in[4];
  float* out = (float*)d_out;

  char* ws  = (char*)d_ws;
  short* vT  = (short*)(ws);                          // 2 MB
  short* BmT = (short*)(ws + (size_t)(2  << 20));     // 25.5 MB
  short* SF  = (short*)(ws + (size_t)(32 << 20));     // 107 MB

  k_transpose<<<dim3(256),  dim3(256),  0, stream>>>(vertex, vT);
  k_bmt      <<<dim3(512),  dim3(512),  0, stream>>>(W, Wc, BmT);
  k_init     <<<dim3(2048), dim3(512),  0, stream>>>(B, out);
  g_supports <<<dim3(816),  dim3(1024), 0, stream>>>(A, vT, SF);
  g_out      <<<dim3(544),  dim3(512),  0, stream>>>(SF, BmT, out);
}

// Round 6
// 503.840 us; speedup vs baseline: 1.1280x; 1.1280x over previous
//
#include <hip/hip_runtime.h>
#include <hip/hip_bf16.h>

typedef __attribute__((ext_vector_type(8))) short short8;
typedef __attribute__((ext_vector_type(4))) float f32x4;

#define NN    2048
#define DDIM  512
#define HDIM  512
#define PP    51
#define NBASE 30
#define PD    26112   // PP*DDIM
#define NKC   17      // split-K factor in G2

static __device__ __forceinline__ short f2bf(float f) {
  __hip_bfloat16 h = __float2bfloat16(f);
  short s;
  __builtin_memcpy(&s, &h, 2);
  return s;
}

#define GLOAD16(gsrc, ldst)                                                              \
  __builtin_amdgcn_global_load_lds((const __attribute__((address_space(1))) void*)(gsrc),\
                                   (__attribute__((address_space(3))) void*)(ldst),      \
                                   16, 0, 0)

// ---------------------------------------------------------------------------
// K0: vertex [2048,512] f32 -> vT [512,2048] bf16
// ---------------------------------------------------------------------------
__global__ __launch_bounds__(256) void k_transpose(const float* __restrict__ vx,
                                                   short* __restrict__ vT) {
  __shared__ float tile[64][68];
  const int t  = threadIdx.x;
  const int mt = blockIdx.x & 31, dt = blockIdx.x >> 5;
  const int m0 = mt * 64, d0 = dt * 64;

  const int r  = t >> 2;
  const int c0 = (t & 3) * 16;
  const float* src = vx + (size_t)(m0 + r) * DDIM + d0 + c0;
#pragma unroll
  for (int j = 0; j < 4; ++j) {
    f32x4 v = *(const f32x4*)(src + j * 4);
    tile[r][c0 + j * 4 + 0] = v[0];
    tile[r][c0 + j * 4 + 1] = v[1];
    tile[r][c0 + j * 4 + 2] = v[2];
    tile[r][c0 + j * 4 + 3] = v[3];
  }
  __syncthreads();
  const int c  = t >> 2;
  const int r0 = (t & 3) * 16;
  short8 o0, o1;
#pragma unroll
  for (int j = 0; j < 8; ++j) {
    o0[j] = f2bf(tile[r0 + j][c]);
    o1[j] = f2bf(tile[r0 + 8 + j][c]);
  }
  short* dst = vT + (size_t)(d0 + c) * NN + m0 + r0;
  *(short8*)(dst)     = o0;
  *(short8*)(dst + 8) = o1;
}

// ---------------------------------------------------------------------------
// K1: BmT [512][26112] bf16 ; BmT[h][d'*51+p] = sum_b Wc[p,b]*W[(b*512+d')*512+h]
// ---------------------------------------------------------------------------
__global__ __launch_bounds__(512) void k_bmt(const float* __restrict__ W,
                                             const float* __restrict__ Wc,
                                             short* __restrict__ BmT) {
  __shared__ float wcs[PP * NBASE];
  __shared__ short Lt[HDIM * PP];
  const int t  = threadIdx.x;
  const int dp = blockIdx.x;

  for (int i = t; i < PP * NBASE; i += 512) wcs[i] = Wc[i];

  float wv[NBASE];
#pragma unroll
  for (int b = 0; b < NBASE; ++b)
    wv[b] = W[((size_t)(b * DDIM + dp)) * HDIM + t];
  __syncthreads();

#pragma unroll 1
  for (int p = 0; p < PP; ++p) {
    float acc = 0.f;
#pragma unroll
    for (int b = 0; b < NBASE; ++b) acc += wcs[p * NBASE + b] * wv[b];
    Lt[t * PP + p] = f2bf(acc);
  }
  __syncthreads();

  for (int idx = t; idx < HDIM * PP; idx += 512) {
    const int h = idx / PP;
    const int p = idx - h * PP;
    BmT[(size_t)h * PD + dp * PP + p] = Lt[idx];
  }
}

// ---------------------------------------------------------------------------
// G1: SF[n][p*512+d] = sum_m A[p,n,m]*vertex[m,d]   (round-3 winner, verbatim)
// grid 816 = 51p x 16n ; 1024 thr (16 waves, 2x8) ; tile 128(n) x 512(d) x BK64
// ---------------------------------------------------------------------------
__global__ __launch_bounds__(1024, 4) void g_supports(const float* __restrict__ A,
                                                      const short* __restrict__ vT,
                                                      short* __restrict__ SF) {
  __shared__ __align__(16) char Asb[128 * 64 * 2];        // 16 KB
  __shared__ __align__(16) char Bsb[2][512 * 64 * 2];     // 2 x 64 KB
  const int t    = threadIdx.x;
  const int p    = blockIdx.x >> 4;
  const int n0   = (blockIdx.x & 15) << 7;
  const int lane = t & 63, w = t >> 6;        // 16 waves
  const int wr = w >> 3, wc = w & 7;          // 2 x 8 wave grid
  const int l15 = lane & 15, q4 = lane >> 4;

  const int arow = t >> 3;
  const int ac16 = (t & 7) << 4;
  char* aw = Asb + arow * 128 + (ac16 ^ ((arow & 7) << 4));
  const float* Arow = A + (size_t)p * NN * NN + (size_t)(n0 + arow) * NN + ((t & 7) << 3);

  f32x4 acc[4][4];
#pragma unroll
  for (int i = 0; i < 4; ++i)
#pragma unroll
    for (int j = 0; j < 4; ++j) acc[i][j] = (f32x4){0.f, 0.f, 0.f, 0.f};

  f32x4 ar0, ar1;

#define G1_ISSUE_B(buf, kt)                                                        \
  {                                                                                \
    _Pragma("unroll")                                                              \
    for (int i = 0; i < 4; ++i) {                                                  \
      const int L   = t * 16 + i * 16384;                                          \
      const int row = L >> 7;                                                      \
      const int cb  = L & 127;                                                     \
      const char* g = (const char*)vT + (size_t)row * (NN * 2) + (kt) * 128        \
                    + (cb ^ ((row & 7) << 4));                                     \
      GLOAD16(g, Bsb[buf] + L);                                                    \
    }                                                                              \
  }

#define G1_ISSUE_A(kt)                                                             \
  {                                                                                \
    const f32x4* s = (const f32x4*)(Arow + (kt) * 64);                             \
    ar0 = s[0]; ar1 = s[1];                                                        \
  }

#define G1_STAGE_A()                                                               \
  {                                                                                \
    short8 s0;                                                                     \
    _Pragma("unroll")                                                              \
    for (int j = 0; j < 4; ++j) {                                                  \
      s0[j]     = f2bf(ar0[j]);                                                    \
      s0[j + 4] = f2bf(ar1[j]);                                                    \
    }                                                                              \
    *(short8*)aw = s0;                                                             \
  }

#define G1_COMPUTE(buf)                                                            \
  {                                                                                \
    _Pragma("unroll")                                                              \
    for (int ks = 0; ks < 2; ++ks) {                                               \
      const int kb = ks * 64 + q4 * 16;                                            \
      short8 af[4], bfr[4];                                                        \
      _Pragma("unroll")                                                            \
      for (int mi = 0; mi < 4; ++mi) {                                             \
        const int row = wr * 64 + mi * 16 + l15;                                   \
        af[mi] = *(const short8*)(Asb + row * 128 + (kb ^ ((row & 7) << 4)));      \
      }                                                                            \
      _Pragma("unroll")                                                            \
      for (int ni = 0; ni < 4; ++ni) {                                             \
        const int row = wc * 64 + ni * 16 + l15;                                   \
        bfr[ni] = *(const short8*)(Bsb[buf] + row * 128 + (kb ^ ((row & 7) << 4)));\
      }                                                                            \
      _Pragma("unroll")                                                            \
      for (int mi = 0; mi < 4; ++mi)                                               \
        _Pragma("unroll")                                                          \
        for (int ni = 0; ni < 4; ++ni)                                             \
          acc[mi][ni] = __builtin_amdgcn_mfma_f32_16x16x32_bf16(af[mi], bfr[ni],   \
                                                                acc[mi][ni], 0, 0, 0);\
    }                                                                              \
  }

  // ---- prologue ----
  G1_ISSUE_B(0, 0);
  G1_ISSUE_A(0);
  G1_STAGE_A();
  G1_ISSUE_B(1, 1);
  G1_ISSUE_A(1);
  asm volatile("s_waitcnt lgkmcnt(0)" ::: "memory");
  __builtin_amdgcn_sched_barrier(0);
  __builtin_amdgcn_s_barrier();

  int cur = 0;
  for (int kt = 0; kt < 31; ++kt) {
    __builtin_amdgcn_s_setprio(1);
    G1_COMPUTE(cur);
    __builtin_amdgcn_s_setprio(0);

    asm volatile("s_waitcnt vmcnt(2)" ::: "memory");
    __builtin_amdgcn_sched_barrier(0);
    __builtin_amdgcn_s_barrier();

    G1_STAGE_A();
    if (kt + 2 < 32) {
      G1_ISSUE_B(cur, kt + 2);
      G1_ISSUE_A(kt + 2);
    }
    asm volatile("s_waitcnt lgkmcnt(0)" ::: "memory");
    __builtin_amdgcn_sched_barrier(0);
    __builtin_amdgcn_s_barrier();
    cur ^= 1;
  }
  G1_COMPUTE(cur);

#pragma unroll
  for (int mi = 0; mi < 4; ++mi) {
    const int nr = n0 + wr * 64 + mi * 16 + q4 * 4;
#pragma unroll
    for (int ni = 0; ni < 4; ++ni) {
      const int dc = p * DDIM + wc * 64 + ni * 16 + l15;
#pragma unroll
      for (int qq = 0; qq < 4; ++qq)
        SF[(size_t)(nr + qq) * PD + dc] = f2bf(acc[mi][ni][qq]);
    }
  }
#undef G1_ISSUE_B
#undef G1_ISSUE_A
#undef G1_STAGE_A
#undef G1_COMPUTE
}

// ---------------------------------------------------------------------------
// G2: part[kc][n][h] = sum_{r in chunk kc} SF[n,r]*BmT[h,r]
// Same main loop as round 1; epilogue = plain coalesced stores (NO atomics).
// grid 544 = 17kc x 16n x 2h ; tile 128 x 256 x BK64 ; 48 KB LDS
// ---------------------------------------------------------------------------
__global__ __launch_bounds__(512) void g_out_part(const short* __restrict__ SF,
                                                  const short* __restrict__ BmT,
                                                  float* __restrict__ part) {
  __shared__ __align__(16) char Asb[128 * 64 * 2];
  __shared__ __align__(16) char Bsb[256 * 64 * 2];
  const int t   = threadIdx.x;
  const int bid = blockIdx.x;
  const int kc  = bid >> 5;
  const int rem = bid & 31;
  const int n0  = (rem >> 1) * 128;
  const int h0  = (rem & 1) * 256;
  const int rbase = kc * 1536;
  const int lane = t & 63, w = t >> 6;
  const int wr = w >> 2, wc = w & 3;
  const int l15 = lane & 15, q4 = lane >> 4;

  f32x4 acc[4][4];
#pragma unroll
  for (int i = 0; i < 4; ++i)
#pragma unroll
    for (int j = 0; j < 4; ++j) acc[i][j] = (f32x4){0.f, 0.f, 0.f, 0.f};

  for (int kt = 0; kt < 24; ++kt) {
    const int rk = rbase + (kt << 6);
    __syncthreads();
#pragma unroll
    for (int i = 0; i < 2; ++i) {
      const int L   = t * 16 + i * 8192;
      const int row = L >> 7, cb = L & 127;
      const char* g = (const char*)SF + ((size_t)(n0 + row) * PD + rk) * 2
                    + (cb ^ ((row & 7) << 4));
      GLOAD16(g, Asb + L);
    }
#pragma unroll
    for (int i = 0; i < 4; ++i) {
      const int L   = t * 16 + i * 8192;
      const int row = L >> 7, cb = L & 127;
      const char* g = (const char*)BmT + ((size_t)(h0 + row) * PD + rk) * 2
                    + (cb ^ ((row & 7) << 4));
      GLOAD16(g, Bsb + L);
    }
    __syncthreads();
#pragma unroll
    for (int ks = 0; ks < 2; ++ks) {
      const int kb = ks * 64 + q4 * 16;
      short8 af[4], bfr[4];
#pragma unroll
      for (int mi = 0; mi < 4; ++mi) {
        const int row = wr * 64 + mi * 16 + l15;
        af[mi] = *(const short8*)(Asb + row * 128 + (kb ^ ((row & 7) << 4)));
      }
#pragma unroll
      for (int ni = 0; ni < 4; ++ni) {
        const int row = wc * 64 + ni * 16 + l15;
        bfr[ni] = *(const short8*)(Bsb + row * 128 + (kb ^ ((row & 7) << 4)));
      }
#pragma unroll
      for (int mi = 0; mi < 4; ++mi)
#pragma unroll
        for (int ni = 0; ni < 4; ++ni)
          acc[mi][ni] = __builtin_amdgcn_mfma_f32_16x16x32_bf16(af[mi], bfr[ni],
                                                                acc[mi][ni], 0, 0, 0);
    }
  }

  float* dst = part + (size_t)kc * (NN * HDIM);
#pragma unroll
  for (int mi = 0; mi < 4; ++mi) {
    const int nr = n0 + wr * 64 + mi * 16 + q4 * 4;
#pragma unroll
    for (int ni = 0; ni < 4; ++ni) {
      const int hc = h0 + wc * 64 + ni * 16 + l15;
#pragma unroll
      for (int qq = 0; qq < 4; ++qq)
        dst[(size_t)(nr + qq) * HDIM + hc] = acc[mi][ni][qq];
    }
  }
}

// ---------------------------------------------------------------------------
// K3: out[n,h] = B[h] + sum_kc part[kc][n][h]    (f32x4, fully coalesced)
// ---------------------------------------------------------------------------
__global__ __launch_bounds__(256) void k_reduce(const float* __restrict__ part,
                                                const float* __restrict__ B,
                                                float* __restrict__ out) {
  const int flat = (blockIdx.x * 256 + threadIdx.x) * 4;   // 0 .. 1048572
  f32x4 s = *(const f32x4*)(B + (flat & (HDIM - 1)));
#pragma unroll
  for (int kc = 0; kc < NKC; ++kc)
    s += *(const f32x4*)(part + (size_t)kc * (NN * HDIM) + flat);
  *(f32x4*)(out + flat) = s;
}

// ---------------------------------------------------------------------------
// Workspace map (ws ~3.3 GB):
//   vT   [  0 MiB,   2 MiB)   512*2048 bf16        = 2 MiB
//   BmT  [  2 MiB,  27.5MiB)  512*26112 bf16       = 25.5 MiB
//   SF   [ 32 MiB, 134 MiB)   2048*26112 bf16      = 102 MiB   <-- was the r5 bug
//   part [144 MiB, 215.3MiB)  17*2048*512 f32      = 68 MiB
// ---------------------------------------------------------------------------
extern "C" void kernel_launch(void* const* d_in, const int* in_sizes, int n_in,
                              void* d_out, int out_size, void* d_ws, size_t ws_size,
                              hipStream_t stream) {
  const float* vertex = (const float*)d_in[0];
  const float* A      = (const float*)d_in[1];
  const float* W      = (const float*)d_in[2];
  const float* Wc     = (const float*)d_in[3];
  const float* B      = (const float*)d_in[4];
  float* out = (float*)d_out;

  char* ws   = (char*)d_ws;
  short* vT   = (short*)(ws);
  short* BmT  = (short*)(ws + (size_t)(2   << 20));
  short* SF   = (short*)(ws + (size_t)(32  << 20));
  float* part = (float*)(ws + (size_t)(144 << 20));

  k_transpose<<<dim3(256),  dim3(256),  0, stream>>>(vertex, vT);
  k_bmt      <<<dim3(512),  dim3(512),  0, stream>>>(W, Wc, BmT);
  g_supports <<<dim3(816),  dim3(1024), 0, stream>>>(A, vT, SF);
  g_out_part <<<dim3(544),  dim3(512),  0, stream>>>(SF, BmT, part);
  k_reduce   <<<dim3(1024), dim3(256),  0, stream>>>(part, B, out);
}